// Round 3
// baseline (10106.116 us; speedup 1.0000x reference)
//
#include <hip/hip_runtime.h>
#include <hip/hip_bf16.h>

#define T_ 64
#define B_ 128
#define S_ 512
#define E_ 256
#define H_ 512
#define TB_ (T_*B_)
#define H3_ (3*H_)

typedef __attribute__((ext_vector_type(8))) short short8;
typedef __attribute__((ext_vector_type(4))) short short4v;
typedef __attribute__((ext_vector_type(4))) float f32x4;
typedef __bf16 bf16x8 __attribute__((ext_vector_type(8)));

__device__ __forceinline__ short f2bf(float x){
    unsigned u = __builtin_bit_cast(unsigned, x);
    u += 0x7FFFu + ((u >> 16) & 1u);
    return (short)(u >> 16);
}
__device__ __forceinline__ float bf2f(short h){
    unsigned u = ((unsigned)(unsigned short)h) << 16;
    return __builtin_bit_cast(float, u);
}

__device__ __forceinline__ f32x4 mfma16(short8 a, short8 b, f32x4 c){
    return __builtin_amdgcn_mfma_f32_16x16x32_bf16(
        __builtin_bit_cast(bf16x8, a), __builtin_bit_cast(bf16x8, b), c, 0, 0, 0);
}

__device__ __forceinline__ f32x4 zero4(){ f32x4 z; z[0]=0.f; z[1]=0.f; z[2]=0.f; z[3]=0.f; return z; }

// load 8 consecutive fp32, produce hi/lo bf16 split fragments
__device__ __forceinline__ void load_cvt_frag(const float* __restrict__ p, short8& hi, short8& lo){
    const f32x4 v0 = *(const f32x4*)(p);
    const f32x4 v1 = *(const f32x4*)(p + 4);
    #pragma unroll
    for(int i=0;i<8;++i){
        float x = (i<4) ? v0[i] : v1[i-4];
        short h = f2bf(x);
        hi[i] = h;
        lo[i] = f2bf(x - bf2f(h));
    }
}
__device__ __forceinline__ short8 load_cvt8(const float* __restrict__ p){
    const f32x4 v0 = *(const f32x4*)(p);
    const f32x4 v1 = *(const f32x4*)(p + 4);
    short8 r;
    #pragma unroll
    for(int i=0;i<8;++i){ float x = (i<4)? v0[i] : v1[i-4]; r[i] = f2bf(x); }
    return r;
}

// ---------------- K0: weight prep (fp32 -> bf16 hi/lo splits) ----------------
__global__ __launch_bounds__(256) void k_prep(
    const float* __restrict__ w_hh, const float* __restrict__ w_ih,
    const float* __restrict__ w_in, const float* __restrict__ w_out,
    short* __restrict__ wh_hi, short* __restrict__ wh_lo,
    short* __restrict__ wi_hi, short* __restrict__ wi_lo,
    short* __restrict__ win_hi, short* __restrict__ win_lo,
    short* __restrict__ wout_bf)
{
    const int stride = gridDim.x * 256;
    const int i0 = blockIdx.x * 256 + threadIdx.x;
    for(int i = i0; i < H3_*H_; i += stride){
        float x = w_hh[i]; short h = f2bf(x); wh_hi[i] = h; wh_lo[i] = f2bf(x - bf2f(h));
    }
    for(int i = i0; i < H3_*E_; i += stride){
        float x = w_ih[i]; short h = f2bf(x); wi_hi[i] = h; wi_lo[i] = f2bf(x - bf2f(h));
    }
    for(int i = i0; i < H_*H_; i += stride){
        float x = w_in[i]; short h = f2bf(x); win_hi[i] = h; win_lo[i] = f2bf(x - bf2f(h));
    }
    for(int i = i0; i < H_*2*H_; i += stride){
        wout_bf[i] = f2bf(w_out[i]);
    }
}

// ---------------- K2: persistent GRU recurrence, all 64 steps ----------------
// 8 blocks x 1024 threads (16 waves). Block owns batch rows [16*bx, 16*bx+16)
// for ALL steps: no cross-block deps (batch chains are independent; h round-
// trips through global h_all[t], distinct buffer per step -> 1 barrier/step).
// Wave w covers j-groups {16w, 256+16w}, 3 gates each, split-3 bf16 MFMA.
__global__ __launch_bounds__(1024) void k_rec(
    const float* __restrict__ hidden, const float* __restrict__ input,
    const short* __restrict__ wh_hi, const short* __restrict__ wh_lo,
    const short* __restrict__ wi_hi, const short* __restrict__ wi_lo,
    const float* __restrict__ b_ih, const float* __restrict__ b_hh,
    float* __restrict__ h_all)
{
    const int tid  = threadIdx.x;
    const int wave = tid >> 6;
    const int lane = tid & 63;
    const int m0   = blockIdx.x * 16;
    const int nc   = lane & 15;
    const int kb   = (lane >> 4) * 8;
    const int rowA = m0 + (lane & 15);
    const int rq4  = (lane >> 4) << 2;
    const int j0a[2] = { wave*16, (wave + 16)*16 };

    // hoist biases (j fixed per wave)
    float bihR[2], bhhR[2], bihZ[2], bhhZ[2], bihN[2], bhhN[2];
    #pragma unroll
    for(int jj = 0; jj < 2; ++jj){
        const int j = j0a[jj] + nc;
        bihR[jj] = b_ih[j];        bhhR[jj] = b_hh[j];
        bihZ[jj] = b_ih[H_+j];     bhhZ[jj] = b_hh[H_+j];
        bihN[jj] = b_ih[2*H_+j];   bhhN[jj] = b_hh[2*H_+j];
    }

    for(int t = 0; t < T_; ++t){
        const float* __restrict__ hprev = (t == 0) ? hidden
                                                   : (h_all + (size_t)(t-1)*B_*H_);
        f32x4 aR[2]  = {zero4(), zero4()};
        f32x4 aZ[2]  = {zero4(), zero4()};
        f32x4 aNH[2] = {zero4(), zero4()};
        f32x4 aNX[2] = {zero4(), zero4()};

        // h-phase: K = 512
        const float* __restrict__ hrow = hprev + (size_t)rowA*H_;
        for(int k0 = 0; k0 < H_; k0 += 32){
            short8 ahi, alo;
            load_cvt_frag(hrow + k0 + kb, ahi, alo);
            #pragma unroll
            for(int jj = 0; jj < 2; ++jj){
                #pragma unroll
                for(int g = 0; g < 3; ++g){
                    const size_t wr = (size_t)(g*H_ + j0a[jj] + nc)*H_ + k0 + kb;
                    const short8 bh = *(const short8*)(wh_hi + wr);
                    const short8 bl = *(const short8*)(wh_lo + wr);
                    f32x4& a = (g==0) ? aR[jj] : (g==1) ? aZ[jj] : aNH[jj];
                    a = mfma16(ahi, bh, a);
                    a = mfma16(alo, bh, a);
                    a = mfma16(ahi, bl, a);
                }
            }
        }
        // x-phase: K = 256
        const float* __restrict__ xrow = input + ((size_t)t*B_ + rowA)*E_;
        for(int k0 = 0; k0 < E_; k0 += 32){
            short8 ahi, alo;
            load_cvt_frag(xrow + k0 + kb, ahi, alo);
            #pragma unroll
            for(int jj = 0; jj < 2; ++jj){
                #pragma unroll
                for(int g = 0; g < 3; ++g){
                    const size_t wr = (size_t)(g*H_ + j0a[jj] + nc)*E_ + k0 + kb;
                    const short8 bh = *(const short8*)(wi_hi + wr);
                    const short8 bl = *(const short8*)(wi_lo + wr);
                    f32x4& a = (g==0) ? aR[jj] : (g==1) ? aZ[jj] : aNX[jj];
                    a = mfma16(ahi, bh, a);
                    a = mfma16(alo, bh, a);
                    a = mfma16(ahi, bl, a);
                }
            }
        }
        // gates epilogue -> h_all[t]
        float* __restrict__ hcur = h_all + (size_t)t*B_*H_;
        #pragma unroll
        for(int jj = 0; jj < 2; ++jj){
            const int j = j0a[jj] + nc;
            #pragma unroll
            for(int r = 0; r < 4; ++r){
                const int row = m0 + rq4 + r;
                const float hp = hprev[(size_t)row*H_ + j];
                const float rr = 1.f/(1.f + expf(-(aR[jj][r] + bihR[jj] + bhhR[jj])));
                const float zz = 1.f/(1.f + expf(-(aZ[jj][r] + bihZ[jj] + bhhZ[jj])));
                const float nn = tanhf(aNX[jj][r] + bihN[jj] + rr*(aNH[jj][r] + bhhN[jj]));
                hcur[(size_t)row*H_ + j] = (1.f - zz)*nn + zz*hp;
            }
        }
        __syncthreads();   // all h_all[t] writes visible before step t+1 reads
    }
}

// ---------------- K3: tmat = h_all @ w_in^T  (split-3, fp32 out) -------------
__global__ __launch_bounds__(256) void k_tmat(
    const float* __restrict__ h_all,
    const short* __restrict__ win_hi, const short* __restrict__ win_lo,
    float* __restrict__ tmat)
{
    const int lane = threadIdx.x & 63;
    const int wv = threadIdx.x >> 6;
    const int m0 = blockIdx.x*64 + wv*16;
    const int n0 = blockIdx.y*64;
    const int rowA = m0 + (lane & 15);
    const int kb = (lane >> 4) * 8;
    const int nc = lane & 15;
    f32x4 acc[4] = {zero4(), zero4(), zero4(), zero4()};
    for(int k0 = 0; k0 < H_; k0 += 32){
        short8 ahi, alo;
        load_cvt_frag(h_all + (size_t)rowA*H_ + k0 + kb, ahi, alo);
        #pragma unroll
        for(int nj = 0; nj < 4; ++nj){
            const int n = n0 + nj*16 + nc;
            const short8 bh = *(const short8*)(win_hi + n*H_ + k0 + kb);
            const short8 bl = *(const short8*)(win_lo + n*H_ + k0 + kb);
            acc[nj] = mfma16(ahi, bh, acc[nj]);
            acc[nj] = mfma16(alo, bh, acc[nj]);
            acc[nj] = mfma16(ahi, bl, acc[nj]);
        }
    }
    const int rbase = m0 + ((lane >> 4) << 2);
    #pragma unroll
    for(int nj = 0; nj < 4; ++nj){
        const int n = n0 + nj*16 + nc;
        #pragma unroll
        for(int r = 0; r < 4; ++r) tmat[(size_t)(rbase + r)*H_ + n] = acc[nj][r];
    }
}

// ---------------- K4: scores[t,b,s] = tmat[t,b,:]·ctx[s,b,:]  (split-3) ------
__global__ __launch_bounds__(256) void k_scores(
    const float* __restrict__ tmat, const float* __restrict__ ctx,
    float* __restrict__ attn)
{
    const int b = blockIdx.y;
    const int lane = threadIdx.x & 63;
    const int wv = threadIdx.x >> 6;
    const int m0 = wv*16;             // T rows
    const int n0 = blockIdx.x*64;     // S cols
    const int kb = (lane >> 4) * 8;
    const int nc = lane & 15;
    const float* Ab = tmat + (size_t)b*H_;
    const float* Bb = ctx  + (size_t)b*H_;
    const int rowA = m0 + (lane & 15);
    f32x4 acc[4] = {zero4(), zero4(), zero4(), zero4()};
    for(int k0 = 0; k0 < H_; k0 += 32){
        short8 ahi, alo;
        load_cvt_frag(Ab + (size_t)rowA*(B_*H_) + k0 + kb, ahi, alo);
        #pragma unroll
        for(int nj = 0; nj < 4; ++nj){
            const int n = n0 + nj*16 + nc;
            short8 bh, bl;
            load_cvt_frag(Bb + (size_t)n*(B_*H_) + k0 + kb, bh, bl);
            acc[nj] = mfma16(ahi, bh, acc[nj]);
            acc[nj] = mfma16(alo, bh, acc[nj]);
            acc[nj] = mfma16(ahi, bl, acc[nj]);
        }
    }
    const int rbase = m0 + ((lane >> 4) << 2);
    #pragma unroll
    for(int nj = 0; nj < 4; ++nj){
        const int s = n0 + nj*16 + nc;
        #pragma unroll
        for(int r = 0; r < 4; ++r){
            const int t = rbase + r;
            attn[((size_t)t*B_ + b)*S_ + s] = acc[nj][r];
        }
    }
}

// ---------------- K5: row softmax over S, in-place on attn -------------------
__global__ __launch_bounds__(64) void k_softmax(float* __restrict__ attn){
    const int row = blockIdx.x;
    float* p = attn + (size_t)row*S_;
    const int lane = threadIdx.x;
    float v[8];
    float mx = -1e30f;
    #pragma unroll
    for(int i = 0; i < 8; ++i){ v[i] = p[lane + i*64]; mx = fmaxf(mx, v[i]); }
    #pragma unroll
    for(int o = 32; o; o >>= 1) mx = fmaxf(mx, __shfl_xor(mx, o));
    float sm = 0.f;
    #pragma unroll
    for(int i = 0; i < 8; ++i){ v[i] = expf(v[i] - mx); sm += v[i]; }
    #pragma unroll
    for(int o = 32; o; o >>= 1) sm += __shfl_xor(sm, o);
    const float inv = 1.f/sm;
    #pragma unroll
    for(int i = 0; i < 8; ++i) p[lane + i*64] = v[i]*inv;
}

// ---------------- K6: wc[t,b,h] = sum_s a[t,b,s]*ctx[s,b,h]  (plain bf16) ----
#define KP 40
__global__ __launch_bounds__(256) void k_wc(
    const float* __restrict__ attn, const float* __restrict__ ctx,
    float* __restrict__ wc)
{
    const int b = blockIdx.y;
    const int n0 = blockIdx.x*64;
    __shared__ alignas(16) short As[64*KP];
    __shared__ alignas(16) short Bs[64*KP];
    const int lane = threadIdx.x & 63;
    const int wv = threadIdx.x >> 6;
    const int m0 = wv*16;
    const int nc = lane & 15;
    const int kb = (lane >> 4) * 8;
    f32x4 acc[4] = {zero4(), zero4(), zero4(), zero4()};
    for(int k0 = 0; k0 < S_; k0 += 32){
        __syncthreads();
        #pragma unroll
        for(int p = 0; p < 2; ++p){
            int f4 = threadIdx.x + p*256;
            int row = f4 >> 3, kq = f4 & 7;
            const float* src = attn + ((size_t)row*B_ + b)*S_ + k0 + kq*4;
            f32x4 vv = *(const f32x4*)src;
            short4v s4;
            #pragma unroll
            for(int q = 0; q < 4; ++q) s4[q] = f2bf(vv[q]);
            *(short4v*)(As + row*KP + kq*4) = s4;
        }
        #pragma unroll
        for(int p = 0; p < 2; ++p){
            int f4 = threadIdx.x + p*256;
            int s = f4 >> 4, hq = f4 & 15;
            const float* src = ctx + ((size_t)(k0 + s)*B_ + b)*H_ + n0 + hq*4;
            f32x4 vv = *(const f32x4*)src;
            #pragma unroll
            for(int q = 0; q < 4; ++q) Bs[(hq*4 + q)*KP + s] = f2bf(vv[q]);
        }
        __syncthreads();
        const short8 af = *(const short8*)(As + (m0 + (lane & 15))*KP + kb);
        #pragma unroll
        for(int nj = 0; nj < 4; ++nj){
            const short8 bf = *(const short8*)(Bs + (nj*16 + nc)*KP + kb);
            acc[nj] = mfma16(af, bf, acc[nj]);
        }
    }
    const int rbase = m0 + ((lane >> 4) << 2);
    #pragma unroll
    for(int nj = 0; nj < 4; ++nj){
        const int h = n0 + nj*16 + nc;
        #pragma unroll
        for(int r = 0; r < 4; ++r){
            const int t = rbase + r;
            wc[((size_t)t*B_ + b)*H_ + h] = acc[nj][r];
        }
    }
}

// ---------------- K7: out = tanh(concat(wc,h) @ w_out^T) (plain bf16) --------
__global__ __launch_bounds__(256) void k_out(
    const float* __restrict__ wc, const float* __restrict__ h_all,
    const short* __restrict__ wout_bf, float* __restrict__ outp)
{
    const int lane = threadIdx.x & 63;
    const int wv = threadIdx.x >> 6;
    const int m0 = blockIdx.x*64 + wv*16;
    const int n0 = blockIdx.y*64;
    const int rowA = m0 + (lane & 15);
    const int kb = (lane >> 4) * 8;
    const int nc = lane & 15;
    f32x4 acc[4] = {zero4(), zero4(), zero4(), zero4()};
    for(int kt = 0; kt < 32; ++kt){
        const int k0 = kt*32;
        const float* src = (k0 < H_) ? (wc + (size_t)rowA*H_ + k0 + kb)
                                     : (h_all + (size_t)rowA*H_ + (k0 - H_) + kb);
        const short8 a = load_cvt8(src);
        #pragma unroll
        for(int nj = 0; nj < 4; ++nj){
            const int n = n0 + nj*16 + nc;
            const short8 bf = *(const short8*)(wout_bf + (size_t)n*(2*H_) + k0 + kb);
            acc[nj] = mfma16(a, bf, acc[nj]);
        }
    }
    const int rbase = m0 + ((lane >> 4) << 2);
    #pragma unroll
    for(int nj = 0; nj < 4; ++nj){
        const int n = n0 + nj*16 + nc;
        #pragma unroll
        for(int r = 0; r < 4; ++r) outp[(size_t)(rbase + r)*H_ + n] = tanhf(acc[nj][r]);
    }
}

// ---------------- K8: pgen at t = T-1, pure fp32 -----------------------------
__global__ __launch_bounds__(64) void k_pgen(
    const float* __restrict__ wc, const float* __restrict__ h_all,
    const float* __restrict__ input, const float* __restrict__ w_pgen,
    const float* __restrict__ b_pgen, float* __restrict__ pg_out)
{
    const int b = blockIdx.x;
    const int lane = threadIdx.x;
    const float* wcb = wc    + ((size_t)(T_-1)*B_ + b)*H_;
    const float* hb  = h_all + ((size_t)(T_-1)*B_ + b)*H_;
    const float* xb  = input + ((size_t)(T_-1)*B_ + b)*E_;
    float s = 0.f;
    for(int k = lane; k < H_; k += 64) s += wcb[k]*w_pgen[k];
    for(int k = lane; k < H_; k += 64) s += hb[k]*w_pgen[H_ + k];
    for(int k = lane; k < E_; k += 64) s += xb[k]*w_pgen[2*H_ + k];
    #pragma unroll
    for(int o = 32; o; o >>= 1) s += __shfl_xor(s, o);
    if(lane == 0) pg_out[b] = 1.f/(1.f + expf(-(s + b_pgen[0])));
}

extern "C" void kernel_launch(void* const* d_in, const int* in_sizes, int n_in,
                              void* d_out, int out_size, void* d_ws, size_t ws_size,
                              hipStream_t stream)
{
    const float* input  = (const float*)d_in[0];
    const float* hidden = (const float*)d_in[1];
    const float* ctx    = (const float*)d_in[2];
    const float* w_ih   = (const float*)d_in[3];
    const float* w_hh   = (const float*)d_in[4];
    const float* b_ih   = (const float*)d_in[5];
    const float* b_hh   = (const float*)d_in[6];
    const float* w_in   = (const float*)d_in[7];
    const float* w_out  = (const float*)d_in[8];
    const float* w_pgen = (const float*)d_in[9];
    const float* b_pgen = (const float*)d_in[10];

    float* outp = (float*)d_out;                       // (T,B,H)
    float* attn = outp + (size_t)T_*B_*H_;             // (T,B,S)
    float* pgo  = attn + (size_t)T_*B_*S_;             // (1,B,1)

    char* ws = (char*)d_ws;
    size_t off = 0;
    auto alloc = [&](size_t bytes) -> void* {
        void* p = ws + off; off += (bytes + 255) & ~(size_t)255; return p;
    };
    short* wh_hi   = (short*)alloc((size_t)H3_*H_*2);
    short* wh_lo   = (short*)alloc((size_t)H3_*H_*2);
    short* wi_hi   = (short*)alloc((size_t)H3_*E_*2);
    short* wi_lo   = (short*)alloc((size_t)H3_*E_*2);
    short* win_hi  = (short*)alloc((size_t)H_*H_*2);
    short* win_lo  = (short*)alloc((size_t)H_*H_*2);
    short* wout_bf = (short*)alloc((size_t)H_*2*H_*2);
    float* h_all   = (float*)alloc((size_t)TB_*H_*4);
    float* tmat    = (float*)alloc((size_t)TB_*H_*4);
    float* wcb     = (float*)alloc((size_t)TB_*H_*4);
    (void)ws_size; (void)in_sizes; (void)n_in; (void)out_size;

    k_prep<<<1024, 256, 0, stream>>>(w_hh, w_ih, w_in, w_out,
                                     wh_hi, wh_lo, wi_hi, wi_lo, win_hi, win_lo, wout_bf);

    // persistent recurrence: one launch for all 64 steps
    k_rec<<<8, 1024, 0, stream>>>(hidden, input, wh_hi, wh_lo, wi_hi, wi_lo,
                                  b_ih, b_hh, h_all);

    k_tmat<<<dim3(128, 8), 256, 0, stream>>>(h_all, win_hi, win_lo, tmat);
    k_scores<<<dim3(8, 128), 256, 0, stream>>>(tmat, ctx, attn);
    k_softmax<<<8192, 64, 0, stream>>>(attn);
    k_wc<<<dim3(8, 128), 256, 0, stream>>>(attn, ctx, wcb);
    k_out<<<dim3(128, 8), 256, 0, stream>>>(wcb, h_all, wout_bf, outp);
    k_pgen<<<128, 64, 0, stream>>>(wcb, h_all, input, w_pgen, b_pgen, pgo);
}

// Round 5
// 2490.911 us; speedup vs baseline: 4.0572x; 4.0572x over previous
//
#include <hip/hip_runtime.h>
#include <hip/hip_bf16.h>

#define T_ 64
#define B_ 128
#define S_ 512
#define E_ 256
#define H_ 512
#define TB_ (T_*B_)
#define H3_ (3*H_)
#define NJ_ 32   // j-tiles in k_rec (barrier group size)
#define NG_ 8    // batch groups in k_rec

typedef __attribute__((ext_vector_type(8))) short short8;
typedef __attribute__((ext_vector_type(4))) short short4v;
typedef __attribute__((ext_vector_type(4))) float f32x4;
typedef __bf16 bf16x8 __attribute__((ext_vector_type(8)));

__device__ __forceinline__ short f2bf(float x){
    unsigned u = __builtin_bit_cast(unsigned, x);
    u += 0x7FFFu + ((u >> 16) & 1u);
    return (short)(u >> 16);
}
__device__ __forceinline__ float bf2f(short h){
    unsigned u = ((unsigned)(unsigned short)h) << 16;
    return __builtin_bit_cast(float, u);
}

__device__ __forceinline__ f32x4 mfma16(short8 a, short8 b, f32x4 c){
    return __builtin_amdgcn_mfma_f32_16x16x32_bf16(
        __builtin_bit_cast(bf16x8, a), __builtin_bit_cast(bf16x8, b), c, 0, 0, 0);
}

__device__ __forceinline__ f32x4 zero4(){ f32x4 z; z[0]=0.f; z[1]=0.f; z[2]=0.f; z[3]=0.f; return z; }

__device__ __forceinline__ void load_cvt_frag(const float* __restrict__ p, short8& hi, short8& lo){
    const f32x4 v0 = *(const f32x4*)(p);
    const f32x4 v1 = *(const f32x4*)(p + 4);
    #pragma unroll
    for(int i=0;i<8;++i){
        float x = (i<4) ? v0[i] : v1[i-4];
        short h = f2bf(x);
        hi[i] = h;
        lo[i] = f2bf(x - bf2f(h));
    }
}
__device__ __forceinline__ short8 load_cvt8(const float* __restrict__ p){
    const f32x4 v0 = *(const f32x4*)(p);
    const f32x4 v1 = *(const f32x4*)(p + 4);
    short8 r;
    #pragma unroll
    for(int i=0;i<8;++i){ float x = (i<4)? v0[i] : v1[i-4]; r[i] = f2bf(x); }
    return r;
}

// ---------------- K0: weight prep + h0 split ---------------------------------
__global__ __launch_bounds__(256) void k_prep(
    const float* __restrict__ w_hh, const float* __restrict__ w_ih,
    const float* __restrict__ w_in, const float* __restrict__ w_out,
    const float* __restrict__ hidden,
    short* __restrict__ wh_hi, short* __restrict__ wh_lo,
    short* __restrict__ wi_hi, short* __restrict__ wi_lo,
    short* __restrict__ win_hi, short* __restrict__ win_lo,
    short* __restrict__ wout_bf,
    short* __restrict__ h_hi, short* __restrict__ h_lo)
{
    const int stride = gridDim.x * 256;
    const int i0 = blockIdx.x * 256 + threadIdx.x;
    for(int i = i0; i < H3_*H_; i += stride){
        float x = w_hh[i]; short h = f2bf(x); wh_hi[i] = h; wh_lo[i] = f2bf(x - bf2f(h));
    }
    for(int i = i0; i < H3_*E_; i += stride){
        float x = w_ih[i]; short h = f2bf(x); wi_hi[i] = h; wi_lo[i] = f2bf(x - bf2f(h));
    }
    for(int i = i0; i < H_*H_; i += stride){
        float x = w_in[i]; short h = f2bf(x); win_hi[i] = h; win_lo[i] = f2bf(x - bf2f(h));
    }
    for(int i = i0; i < H_*2*H_; i += stride){
        wout_bf[i] = f2bf(w_out[i]);
    }
    for(int i = i0; i < B_*H_; i += stride){   // h slot 0 = split(hidden)
        float x = hidden[i]; short h = f2bf(x); h_hi[i] = h; h_lo[i] = f2bf(x - bf2f(h));
    }
}

// ---------------- K2: persistent recurrence, ALL weights in VGPRs ------------
// grid (NJ_=32 j-tiles, NG_=8 batch-groups) = 256 WGs, block 192 (3 waves =
// 3 gates). Wave g holds its gate's 16-col w_hh slice (K=512) AND w_ih slice
// (K=256), hi+lo, in ~192 VGPRs -> zero weight traffic inside the step loop.
// gx is computed in-loop (no 50MB gx buffer). Cross-WG h exchange via
// per-(step,group) device-scope arrive counters (bounded spin).
__global__ __launch_bounds__(192, 1) void k_rec(
    const short* __restrict__ wh_hi, const short* __restrict__ wh_lo,
    const short* __restrict__ wi_hi, const short* __restrict__ wi_lo,
    const float* __restrict__ input,
    const float* __restrict__ b_ih, const float* __restrict__ b_hh,
    short* __restrict__ h_hi, short* __restrict__ h_lo,
    unsigned* __restrict__ bar)
{
    const int tid  = threadIdx.x;
    const int wave = tid >> 6;     // gate: 0=R 1=Z 2=N
    const int lane = tid & 63;
    const int j0   = blockIdx.x * 16;
    const int m0   = blockIdx.y * 16;
    const int nc   = lane & 15;
    const int kb   = (lane >> 4) * 8;
    const int rowA = m0 + (lane & 15);
    const int rq4  = (lane >> 4) << 2;
    const int j    = j0 + nc;

    __shared__ float exch[2][16][16];

    // preload weight fragments (held in VGPRs for all 64 steps)
    short8 whh[16], whl[16];
    {
        const size_t wrow = (size_t)(wave*H_ + j)*H_;
        #pragma unroll
        for(int kk = 0; kk < 16; ++kk){
            whh[kk] = *(const short8*)(wh_hi + wrow + kk*32 + kb);
            whl[kk] = *(const short8*)(wh_lo + wrow + kk*32 + kb);
        }
    }
    short8 wih[8], wil[8];
    {
        const size_t wrow = (size_t)(wave*H_ + j)*E_;
        #pragma unroll
        for(int kk = 0; kk < 8; ++kk){
            wih[kk] = *(const short8*)(wi_hi + wrow + kk*32 + kb);
            wil[kk] = *(const short8*)(wi_lo + wrow + kk*32 + kb);
        }
    }
    // biases: waves 0/1 fold b_ih+b_hh into their exch value; wave 2 keeps split
    const float bsum = b_ih[wave*H_ + j] + b_hh[wave*H_ + j];   // used by waves 0/1
    const float bihN = b_ih[2*H_ + j];
    const float bhhN = b_hh[2*H_ + j];

    for(int t = 0; t < T_; ++t){
        const short* __restrict__ phi = h_hi + (size_t)t*B_*H_;
        const short* __restrict__ plo = h_lo + (size_t)t*B_*H_;

        // wave2: prefetch h_prev values for the epilogue
        float hp[4];
        if (wave == 2){
            #pragma unroll
            for(int r = 0; r < 4; ++r){
                const size_t hidx = (size_t)(m0 + rq4 + r)*H_ + j;
                hp[r] = bf2f(phi[hidx]) + bf2f(plo[hidx]);
            }
        }

        // gh part: K = 512 over h[t] (bf16 hi/lo from global, weights in VGPR)
        f32x4 accH = zero4();
        const size_t abase = (size_t)rowA*H_;
        #pragma unroll
        for(int kk = 0; kk < 16; ++kk){
            const short8 ahi = *(const short8*)(phi + abase + kk*32 + kb);
            const short8 alo = *(const short8*)(plo + abase + kk*32 + kb);
            accH = mfma16(ahi, whh[kk], accH);
            accH = mfma16(alo, whh[kk], accH);
            accH = mfma16(ahi, whl[kk], accH);
        }
        // gx part: K = 256 over x_t (fp32 -> split in-flight)
        f32x4 accX = zero4();
        const float* __restrict__ xrow = input + ((size_t)t*B_ + rowA)*E_;
        #pragma unroll
        for(int kk = 0; kk < 8; ++kk){
            short8 xhi, xlo;
            load_cvt_frag(xrow + kk*32 + kb, xhi, xlo);
            accX = mfma16(xhi, wih[kk], accX);
            accX = mfma16(xlo, wih[kk], accX);
            accX = mfma16(xhi, wil[kk], accX);
        }

        if (wave < 2){
            #pragma unroll
            for(int r = 0; r < 4; ++r)
                exch[wave][rq4 + r][nc] = accH[r] + accX[r] + bsum;
        }
        __syncthreads();
        if (wave == 2){
            short* __restrict__ qhi = h_hi + (size_t)(t+1)*B_*H_;
            short* __restrict__ qlo = h_lo + (size_t)(t+1)*B_*H_;
            #pragma unroll
            for(int r = 0; r < 4; ++r){
                const int row = m0 + rq4 + r;
                const float rr = 1.f/(1.f + expf(-exch[0][rq4+r][nc]));
                const float zz = 1.f/(1.f + expf(-exch[1][rq4+r][nc]));
                const float nn = tanhf(accX[r] + bihN + rr*(accH[r] + bhhN));
                const float hn = (1.f - zz)*nn + zz*hp[r];
                const short hih = f2bf(hn);
                const size_t o = (size_t)row*H_ + j;
                qhi[o] = hih;
                qlo[o] = f2bf(hn - bf2f(hih));
            }
        }
        // publish h[t+1], then barrier across the 32 j-tile WGs of this group
        __threadfence();
        __syncthreads();
        if (tid == 0){
            const unsigned cid = (unsigned)(t*NG_ + blockIdx.y);
            __hip_atomic_fetch_add(&bar[cid], 1u, __ATOMIC_RELEASE, __HIP_MEMORY_SCOPE_AGENT);
            // bounded spin: a true deadlock fails absmax instead of wedging the GPU
            unsigned guard = 0;
            while (__hip_atomic_load(&bar[cid], __ATOMIC_ACQUIRE, __HIP_MEMORY_SCOPE_AGENT) < (unsigned)NJ_){
                __builtin_amdgcn_s_sleep(2);
                if (++guard > (1u<<24)) break;
            }
        }
        __syncthreads();
    }
}

// ---------------- K3: tmat = h_all @ w_in^T  (split-3, fp32 out) -------------
__global__ __launch_bounds__(256) void k_tmat(
    const short* __restrict__ h_hi, const short* __restrict__ h_lo,
    const short* __restrict__ win_hi, const short* __restrict__ win_lo,
    float* __restrict__ tmat)
{
    const int lane = threadIdx.x & 63;
    const int wv = threadIdx.x >> 6;
    const int m0 = blockIdx.x*64 + wv*16;
    const int n0 = blockIdx.y*64;
    const int rowA = m0 + (lane & 15);
    const int kb = (lane >> 4) * 8;
    const int nc = lane & 15;
    f32x4 acc[4] = {zero4(), zero4(), zero4(), zero4()};
    for(int k0 = 0; k0 < H_; k0 += 32){
        const size_t ab = (size_t)(B_ + rowA)*H_ + k0 + kb;   // +B_: skip h0 slot
        const short8 ahi = *(const short8*)(h_hi + ab);
        const short8 alo = *(const short8*)(h_lo + ab);
        #pragma unroll
        for(int nj = 0; nj < 4; ++nj){
            const int n = n0 + nj*16 + nc;
            const short8 bh = *(const short8*)(win_hi + (size_t)n*H_ + k0 + kb);
            const short8 bl = *(const short8*)(win_lo + (size_t)n*H_ + k0 + kb);
            acc[nj] = mfma16(ahi, bh, acc[nj]);
            acc[nj] = mfma16(alo, bh, acc[nj]);
            acc[nj] = mfma16(ahi, bl, acc[nj]);
        }
    }
    const int rbase = m0 + ((lane >> 4) << 2);
    #pragma unroll
    for(int nj = 0; nj < 4; ++nj){
        const int n = n0 + nj*16 + nc;
        #pragma unroll
        for(int r = 0; r < 4; ++r) tmat[(size_t)(rbase + r)*H_ + n] = acc[nj][r];
    }
}

// ---------------- K4: scores[t,b,s] = tmat[t,b,:]·ctx[s,b,:]  (split-3) ------
__global__ __launch_bounds__(256) void k_scores(
    const float* __restrict__ tmat, const float* __restrict__ ctx,
    float* __restrict__ attn)
{
    const int b = blockIdx.y;
    const int lane = threadIdx.x & 63;
    const int wv = threadIdx.x >> 6;
    const int m0 = wv*16;             // T rows
    const int n0 = blockIdx.x*64;     // S cols
    const int kb = (lane >> 4) * 8;
    const int nc = lane & 15;
    const float* Ab = tmat + (size_t)b*H_;
    const float* Bb = ctx  + (size_t)b*H_;
    const int rowA = m0 + (lane & 15);
    f32x4 acc[4] = {zero4(), zero4(), zero4(), zero4()};
    for(int k0 = 0; k0 < H_; k0 += 32){
        short8 ahi, alo;
        load_cvt_frag(Ab + (size_t)rowA*(B_*H_) + k0 + kb, ahi, alo);
        #pragma unroll
        for(int nj = 0; nj < 4; ++nj){
            const int n = n0 + nj*16 + nc;
            short8 bhh, bll;
            load_cvt_frag(Bb + (size_t)n*(B_*H_) + k0 + kb, bhh, bll);
            acc[nj] = mfma16(ahi, bhh, acc[nj]);
            acc[nj] = mfma16(alo, bhh, acc[nj]);
            acc[nj] = mfma16(ahi, bll, acc[nj]);
        }
    }
    const int rbase = m0 + ((lane >> 4) << 2);
    #pragma unroll
    for(int nj = 0; nj < 4; ++nj){
        const int s = n0 + nj*16 + nc;
        #pragma unroll
        for(int r = 0; r < 4; ++r){
            const int t = rbase + r;
            attn[((size_t)t*B_ + b)*S_ + s] = acc[nj][r];
        }
    }
}

// ---------------- K5: row softmax over S, in-place on attn -------------------
__global__ __launch_bounds__(64) void k_softmax(float* __restrict__ attn){
    const int row = blockIdx.x;
    float* p = attn + (size_t)row*S_;
    const int lane = threadIdx.x;
    float v[8];
    float mx = -1e30f;
    #pragma unroll
    for(int i = 0; i < 8; ++i){ v[i] = p[lane + i*64]; mx = fmaxf(mx, v[i]); }
    #pragma unroll
    for(int o = 32; o; o >>= 1) mx = fmaxf(mx, __shfl_xor(mx, o));
    float sm = 0.f;
    #pragma unroll
    for(int i = 0; i < 8; ++i){ v[i] = expf(v[i] - mx); sm += v[i]; }
    #pragma unroll
    for(int o = 32; o; o >>= 1) sm += __shfl_xor(sm, o);
    const float inv = 1.f/sm;
    #pragma unroll
    for(int i = 0; i < 8; ++i) p[lane + i*64] = v[i]*inv;
}

// ---------------- K6: wc[t,b,h] = sum_s a[t,b,s]*ctx[s,b,h]  (plain bf16) ----
#define KP 40
__global__ __launch_bounds__(256) void k_wc(
    const float* __restrict__ attn, const float* __restrict__ ctx,
    float* __restrict__ wc)
{
    const int b = blockIdx.y;
    const int n0 = blockIdx.x*64;
    __shared__ alignas(16) short As[64*KP];
    __shared__ alignas(16) short Bs[64*KP];
    const int lane = threadIdx.x & 63;
    const int wv = threadIdx.x >> 6;
    const int m0 = wv*16;
    const int nc = lane & 15;
    const int kb = (lane >> 4) * 8;
    f32x4 acc[4] = {zero4(), zero4(), zero4(), zero4()};
    for(int k0 = 0; k0 < S_; k0 += 32){
        __syncthreads();
        #pragma unroll
        for(int p = 0; p < 2; ++p){
            int f4 = threadIdx.x + p*256;
            int row = f4 >> 3, kq = f4 & 7;
            const float* src = attn + ((size_t)row*B_ + b)*S_ + k0 + kq*4;
            f32x4 vv = *(const f32x4*)src;
            short4v s4;
            #pragma unroll
            for(int q = 0; q < 4; ++q) s4[q] = f2bf(vv[q]);
            *(short4v*)(As + row*KP + kq*4) = s4;
        }
        #pragma unroll
        for(int p = 0; p < 2; ++p){
            int f4 = threadIdx.x + p*256;
            int s = f4 >> 4, hq = f4 & 15;
            const float* src = ctx + ((size_t)(k0 + s)*B_ + b)*H_ + n0 + hq*4;
            f32x4 vv = *(const f32x4*)src;
            #pragma unroll
            for(int q = 0; q < 4; ++q) Bs[(hq*4 + q)*KP + s] = f2bf(vv[q]);
        }
        __syncthreads();
        const short8 af = *(const short8*)(As + (m0 + (lane & 15))*KP + kb);
        #pragma unroll
        for(int nj = 0; nj < 4; ++nj){
            const short8 bf = *(const short8*)(Bs + (nj*16 + nc)*KP + kb);
            acc[nj] = mfma16(af, bf, acc[nj]);
        }
    }
    const int rbase = m0 + ((lane >> 4) << 2);
    #pragma unroll
    for(int nj = 0; nj < 4; ++nj){
        const int h = n0 + nj*16 + nc;
        #pragma unroll
        for(int r = 0; r < 4; ++r){
            const int t = rbase + r;
            wc[((size_t)t*B_ + b)*H_ + h] = acc[nj][r];
        }
    }
}

// ---------------- K7: out = tanh(concat(wc,h) @ w_out^T) (plain bf16) --------
__global__ __launch_bounds__(256) void k_out(
    const float* __restrict__ wc,
    const short* __restrict__ h_hi,
    const short* __restrict__ wout_bf, float* __restrict__ outp)
{
    const int lane = threadIdx.x & 63;
    const int wv = threadIdx.x >> 6;
    const int m0 = blockIdx.x*64 + wv*16;
    const int n0 = blockIdx.y*64;
    const int rowA = m0 + (lane & 15);
    const int kb = (lane >> 4) * 8;
    const int nc = lane & 15;
    f32x4 acc[4] = {zero4(), zero4(), zero4(), zero4()};
    for(int kt = 0; kt < 32; ++kt){
        const int k0 = kt*32;
        short8 a;
        if (k0 < H_) a = load_cvt8(wc + (size_t)rowA*H_ + k0 + kb);
        else         a = *(const short8*)(h_hi + (size_t)(B_ + rowA)*H_ + (k0 - H_) + kb);
        #pragma unroll
        for(int nj = 0; nj < 4; ++nj){
            const int n = n0 + nj*16 + nc;
            const short8 bf = *(const short8*)(wout_bf + (size_t)n*(2*H_) + k0 + kb);
            acc[nj] = mfma16(a, bf, acc[nj]);
        }
    }
    const int rbase = m0 + ((lane >> 4) << 2);
    #pragma unroll
    for(int nj = 0; nj < 4; ++nj){
        const int n = n0 + nj*16 + nc;
        #pragma unroll
        for(int r = 0; r < 4; ++r) outp[(size_t)(rbase + r)*H_ + n] = tanhf(acc[nj][r]);
    }
}

// ---------------- K8: pgen at t = T-1 ----------------------------------------
__global__ __launch_bounds__(64) void k_pgen(
    const float* __restrict__ wc,
    const short* __restrict__ h_hi, const short* __restrict__ h_lo,
    const float* __restrict__ input, const float* __restrict__ w_pgen,
    const float* __restrict__ b_pgen, float* __restrict__ pg_out)
{
    const int b = blockIdx.x;
    const int lane = threadIdx.x;
    const float* wcb = wc    + ((size_t)(T_-1)*B_ + b)*H_;
    const size_t hbase = (size_t)(T_*B_ + b)*H_;   // slot T_, row b
    const float* xb  = input + ((size_t)(T_-1)*B_ + b)*E_;
    float s = 0.f;
    for(int k = lane; k < H_; k += 64) s += wcb[k]*w_pgen[k];
    for(int k = lane; k < H_; k += 64) s += (bf2f(h_hi[hbase+k]) + bf2f(h_lo[hbase+k]))*w_pgen[H_ + k];
    for(int k = lane; k < E_; k += 64) s += xb[k]*w_pgen[2*H_ + k];
    #pragma unroll
    for(int o = 32; o; o >>= 1) s += __shfl_xor(s, o);
    if(lane == 0) pg_out[b] = 1.f/(1.f + expf(-(s + b_pgen[0])));
}

extern "C" void kernel_launch(void* const* d_in, const int* in_sizes, int n_in,
                              void* d_out, int out_size, void* d_ws, size_t ws_size,
                              hipStream_t stream)
{
    const float* input  = (const float*)d_in[0];
    const float* hidden = (const float*)d_in[1];
    const float* ctx    = (const float*)d_in[2];
    const float* w_ih   = (const float*)d_in[3];
    const float* w_hh   = (const float*)d_in[4];
    const float* b_ih   = (const float*)d_in[5];
    const float* b_hh   = (const float*)d_in[6];
    const float* w_in   = (const float*)d_in[7];
    const float* w_out  = (const float*)d_in[8];
    const float* w_pgen = (const float*)d_in[9];
    const float* b_pgen = (const float*)d_in[10];

    float* outp = (float*)d_out;                       // (T,B,H)
    float* attn = outp + (size_t)T_*B_*H_;             // (T,B,S)
    float* pgo  = attn + (size_t)T_*B_*S_;             // (1,B,1)

    char* ws = (char*)d_ws;
    size_t off = 0;
    auto alloc = [&](size_t bytes) -> void* {
        void* p = ws + off; off += (bytes + 255) & ~(size_t)255; return p;
    };
    short* wh_hi   = (short*)alloc((size_t)H3_*H_*2);
    short* wh_lo   = (short*)alloc((size_t)H3_*H_*2);
    short* wi_hi   = (short*)alloc((size_t)H3_*E_*2);
    short* wi_lo   = (short*)alloc((size_t)H3_*E_*2);
    short* win_hi  = (short*)alloc((size_t)H_*H_*2);
    short* win_lo  = (short*)alloc((size_t)H_*H_*2);
    short* wout_bf = (short*)alloc((size_t)H_*2*H_*2);
    short* h_hi    = (short*)alloc((size_t)(T_+1)*B_*H_*2);   // 65 slots
    short* h_lo    = (short*)alloc((size_t)(T_+1)*B_*H_*2);
    unsigned* bar  = (unsigned*)alloc((size_t)T_*NG_*4);
    float* tmat    = (float*)alloc((size_t)TB_*H_*4);         // 16.8 MB
    float* wcb     = tmat;   // alias: tmat dead after k_scores, wcb born at k_wc
    (void)ws_size; (void)in_sizes; (void)n_in; (void)out_size;
    // total ws footprint ~40.7 MB (R3's proven-safe footprint was ~57 MB)

    k_prep<<<1024, 256, 0, stream>>>(w_hh, w_ih, w_in, w_out, hidden,
                                     wh_hi, wh_lo, wi_hi, wi_lo, win_hi, win_lo,
                                     wout_bf, h_hi, h_lo);

    hipMemsetAsync(bar, 0, (size_t)T_*NG_*4, stream);

    k_rec<<<dim3(NJ_, NG_), 192, 0, stream>>>(wh_hi, wh_lo, wi_hi, wi_lo,
                                              input, b_ih, b_hh, h_hi, h_lo, bar);

    k_tmat<<<dim3(128, 8), 256, 0, stream>>>(h_hi, h_lo, win_hi, win_lo, tmat);
    k_scores<<<dim3(8, 128), 256, 0, stream>>>(tmat, ctx, attn);
    k_softmax<<<8192, 64, 0, stream>>>(attn);
    k_wc<<<dim3(8, 128), 256, 0, stream>>>(attn, ctx, wcb);
    k_out<<<dim3(128, 8), 256, 0, stream>>>(wcb, h_hi, wout_bf, outp);
    k_pgen<<<128, 64, 0, stream>>>(wcb, h_hi, h_lo, input, w_pgen, b_pgen, pgo);
}

// Round 6
// 2080.011 us; speedup vs baseline: 4.8587x; 1.1975x over previous
//
#include <hip/hip_runtime.h>
#include <hip/hip_bf16.h>

#define T_ 64
#define B_ 128
#define S_ 512
#define E_ 256
#define H_ 512
#define TB_ (T_*B_)
#define H3_ (3*H_)
#define NJ_ 32   // j-tiles per batch group (barrier width)
#define NG_ 8    // batch groups (presumed = XCDs)

typedef __attribute__((ext_vector_type(8))) short short8;
typedef __attribute__((ext_vector_type(4))) short short4v;
typedef __attribute__((ext_vector_type(4))) float f32x4;
typedef __bf16 bf16x8 __attribute__((ext_vector_type(8)));

__device__ __forceinline__ short f2bf(float x){
    unsigned u = __builtin_bit_cast(unsigned, x);
    u += 0x7FFFu + ((u >> 16) & 1u);
    return (short)(u >> 16);
}
__device__ __forceinline__ float bf2f(short h){
    unsigned u = ((unsigned)(unsigned short)h) << 16;
    return __builtin_bit_cast(float, u);
}

__device__ __forceinline__ f32x4 mfma16(short8 a, short8 b, f32x4 c){
    return __builtin_amdgcn_mfma_f32_16x16x32_bf16(
        __builtin_bit_cast(bf16x8, a), __builtin_bit_cast(bf16x8, b), c, 0, 0, 0);
}

__device__ __forceinline__ f32x4 zero4(){ f32x4 z; z[0]=0.f; z[1]=0.f; z[2]=0.f; z[3]=0.f; return z; }

__device__ __forceinline__ void load_cvt_frag(const float* __restrict__ p, short8& hi, short8& lo){
    const f32x4 v0 = *(const f32x4*)(p);
    const f32x4 v1 = *(const f32x4*)(p + 4);
    #pragma unroll
    for(int i=0;i<8;++i){
        float x = (i<4) ? v0[i] : v1[i-4];
        short h = f2bf(x);
        hi[i] = h;
        lo[i] = f2bf(x - bf2f(h));
    }
}
__device__ __forceinline__ short8 load_cvt8(const float* __restrict__ p){
    const f32x4 v0 = *(const f32x4*)(p);
    const f32x4 v1 = *(const f32x4*)(p + 4);
    short8 r;
    #pragma unroll
    for(int i=0;i<8;++i){ float x = (i<4)? v0[i] : v1[i-4]; r[i] = f2bf(x); }
    return r;
}

// ---------------- K0: prep: split w_in/w_out/h0/x into bf16 (hi/lo) ----------
__global__ __launch_bounds__(256) void k_prep(
    const float* __restrict__ w_in, const float* __restrict__ w_out,
    const float* __restrict__ hidden, const float* __restrict__ input,
    short* __restrict__ win_hi, short* __restrict__ win_lo,
    short* __restrict__ wout_bf,
    short* __restrict__ h_hi, short* __restrict__ h_lo,
    short* __restrict__ x_hi, short* __restrict__ x_lo)
{
    const int stride = gridDim.x * 256;
    const int i0 = blockIdx.x * 256 + threadIdx.x;
    for(int i = i0; i < H_*H_; i += stride){
        float x = w_in[i]; short h = f2bf(x); win_hi[i] = h; win_lo[i] = f2bf(x - bf2f(h));
    }
    for(int i = i0; i < H_*2*H_; i += stride){
        wout_bf[i] = f2bf(w_out[i]);
    }
    for(int i = i0; i < B_*H_; i += stride){   // h slot 0 = split(hidden)
        float x = hidden[i]; short h = f2bf(x); h_hi[i] = h; h_lo[i] = f2bf(x - bf2f(h));
    }
    for(int i = i0; i < T_*B_*E_; i += stride){
        float x = input[i]; short h = f2bf(x); x_hi[i] = h; x_lo[i] = f2bf(x - bf2f(h));
    }
}

// ---------------- K2: persistent recurrence, w_hh in LDS (guaranteed) --------
// 256 WGs x 192 thr (3 waves = 3 gates). WG = (j-tile jt, batch group grp),
// grp = bid&7 so a group's 32 WGs land on one XCD (round-robin heuristic).
// w_hh slice (48 rows x K=512, hi+lo bf16, XOR-swizzled) lives in LDS
// (100,352 B -> 1 WG/CU, residency GUARANTEED unlike R5's VGPR attempt).
// w_ih slice (16 frags x hi/lo = 64 VGPRs) in registers. x pre-split bf16.
__global__ __launch_bounds__(192, 1) void k_rec(
    const float* __restrict__ w_hh, const float* __restrict__ w_ih,
    const short* __restrict__ x_hi, const short* __restrict__ x_lo,
    const float* __restrict__ b_ih, const float* __restrict__ b_hh,
    short* __restrict__ h_hi, short* __restrict__ h_lo,
    unsigned* __restrict__ bar)
{
    const int tid  = threadIdx.x;
    const int wave = tid >> 6;     // gate: 0=R 1=Z 2=N
    const int lane = tid & 63;
    const int bid  = blockIdx.x;
    const int grp  = bid & 7;      // batch group (presumed XCD)
    const int jt   = bid >> 3;     // j-tile 0..31
    const int j0   = jt * 16;
    const int m0   = grp * 16;
    const int nc   = lane & 15;
    const int kb   = (lane >> 4) * 8;
    const int rowA = m0 + (lane & 15);
    const int rq4  = (lane >> 4) << 2;
    const int j    = j0 + nc;
    const int swz  = (nc & 7) << 3;

    __shared__ alignas(16) short whhH[48][512];   // 48 KiB
    __shared__ alignas(16) short whhL[48][512];   // 48 KiB
    __shared__ float exch[2][16][16];             // 2 KiB  -> total 100,352 B

    // ---- init: split w_hh slice into LDS (one-time) ----
    for(int idx = tid; idx < 48*64; idx += 192){
        const int row = idx >> 6;           // gate*16 + col
        const int ch  = idx & 63;           // 8-elem chunk within K=512
        const int gate = row >> 4, col = row & 15;
        short8 hi, lo;
        load_cvt_frag(w_hh + ((size_t)(gate*H_ + j0 + col))*H_ + ch*8, hi, lo);
        const int kidx = (ch*8) ^ ((row & 7) << 3);   // swizzle key = col&7
        *(short8*)&whhH[row][kidx] = hi;
        *(short8*)&whhL[row][kidx] = lo;
    }
    // ---- init: w_ih slice into VGPRs (64 regs; fallback = cheap L2 re-read) --
    short8 wih[8], wil[8];
    {
        const size_t wrow = (size_t)(wave*H_ + j)*E_;
        #pragma unroll
        for(int kk = 0; kk < 8; ++kk)
            load_cvt_frag(w_ih + wrow + kk*32 + kb, wih[kk], wil[kk]);
    }
    const float bsum = b_ih[wave*H_ + j] + b_hh[wave*H_ + j];   // waves 0/1
    const float bihN = b_ih[2*H_ + j];
    const float bhhN = b_hh[2*H_ + j];
    __syncthreads();

    const int brow = wave*16 + nc;   // this wave's LDS B-row for col nc

    for(int t = 0; t < T_; ++t){
        const short* __restrict__ phi = h_hi + (size_t)t*B_*H_;
        const short* __restrict__ plo = h_lo + (size_t)t*B_*H_;

        // wave2: prefetch h_prev for the epilogue
        float hp[4];
        if (wave == 2){
            #pragma unroll
            for(int r = 0; r < 4; ++r){
                const size_t hidx = (size_t)(m0 + rq4 + r)*H_ + j;
                hp[r] = bf2f(phi[hidx]) + bf2f(plo[hidx]);
            }
        }

        // gh: K = 512, A = h[t] (bf16 hi/lo from global), B = LDS (swizzled)
        f32x4 accH = zero4();
        const size_t ab = (size_t)rowA*H_;
        #pragma unroll
        for(int kk = 0; kk < 16; ++kk){
            const short8 ahi = *(const short8*)(phi + ab + kk*32 + kb);
            const short8 alo = *(const short8*)(plo + ab + kk*32 + kb);
            const int ki = (kk*32 + kb) ^ swz;
            const short8 bh = *(const short8*)&whhH[brow][ki];
            const short8 bl = *(const short8*)&whhL[brow][ki];
            accH = mfma16(ahi, bh, accH);
            accH = mfma16(alo, bh, accH);
            accH = mfma16(ahi, bl, accH);
        }
        // gx: K = 256, A = x_t (pre-split bf16), B = VGPR-resident w_ih slice
        f32x4 accX = zero4();
        const size_t xb0 = ((size_t)t*B_ + rowA)*E_;
        #pragma unroll
        for(int kk = 0; kk < 8; ++kk){
            const short8 xhi = *(const short8*)(x_hi + xb0 + kk*32 + kb);
            const short8 xlo = *(const short8*)(x_lo + xb0 + kk*32 + kb);
            accX = mfma16(xhi, wih[kk], accX);
            accX = mfma16(xlo, wih[kk], accX);
            accX = mfma16(xhi, wil[kk], accX);
        }

        if (wave < 2){
            #pragma unroll
            for(int r = 0; r < 4; ++r)
                exch[wave][rq4 + r][nc] = accH[r] + accX[r] + bsum;
        }
        __syncthreads();
        if (wave == 2){
            short* __restrict__ qhi = h_hi + (size_t)(t+1)*B_*H_;
            short* __restrict__ qlo = h_lo + (size_t)(t+1)*B_*H_;
            #pragma unroll
            for(int r = 0; r < 4; ++r){
                const int row = m0 + rq4 + r;
                const float rr = 1.f/(1.f + expf(-exch[0][rq4+r][nc]));
                const float zz = 1.f/(1.f + expf(-exch[1][rq4+r][nc]));
                const float nn = tanhf(accX[r] + bihN + rr*(accH[r] + bhhN));
                const float hn = (1.f - zz)*nn + zz*hp[r];
                const short hih = f2bf(hn);
                const size_t o = (size_t)row*H_ + j;
                qhi[o] = hih;
                qlo[o] = f2bf(hn - bf2f(hih));
            }
        }
        // publish h[t+1], then barrier across this group's 32 j-tile WGs
        __threadfence();
        __syncthreads();
        if (tid == 0){
            const unsigned cid = (unsigned)((t*NG_ + grp) * 16);   // 64B spacing
            __hip_atomic_fetch_add(&bar[cid], 1u, __ATOMIC_RELEASE, __HIP_MEMORY_SCOPE_AGENT);
            unsigned guard = 0;
            while (__hip_atomic_load(&bar[cid], __ATOMIC_ACQUIRE, __HIP_MEMORY_SCOPE_AGENT) < (unsigned)NJ_){
                __builtin_amdgcn_s_sleep(2);
                if (++guard > (1u<<22)) break;   // deadlock -> wrong answer, not wedge
            }
        }
        __syncthreads();
    }
}

// ---------------- K3: tmat = h_all @ w_in^T  (split-3, fp32 out) -------------
__global__ __launch_bounds__(256) void k_tmat(
    const short* __restrict__ h_hi, const short* __restrict__ h_lo,
    const short* __restrict__ win_hi, const short* __restrict__ win_lo,
    float* __restrict__ tmat)
{
    const int lane = threadIdx.x & 63;
    const int wv = threadIdx.x >> 6;
    const int m0 = blockIdx.x*64 + wv*16;
    const int n0 = blockIdx.y*64;
    const int rowA = m0 + (lane & 15);
    const int kb = (lane >> 4) * 8;
    const int nc = lane & 15;
    f32x4 acc[4] = {zero4(), zero4(), zero4(), zero4()};
    for(int k0 = 0; k0 < H_; k0 += 32){
        const size_t ab = (size_t)(B_ + rowA)*H_ + k0 + kb;   // +B_: skip h0 slot
        const short8 ahi = *(const short8*)(h_hi + ab);
        const short8 alo = *(const short8*)(h_lo + ab);
        #pragma unroll
        for(int nj = 0; nj < 4; ++nj){
            const int n = n0 + nj*16 + nc;
            const short8 bh = *(const short8*)(win_hi + (size_t)n*H_ + k0 + kb);
            const short8 bl = *(const short8*)(win_lo + (size_t)n*H_ + k0 + kb);
            acc[nj] = mfma16(ahi, bh, acc[nj]);
            acc[nj] = mfma16(alo, bh, acc[nj]);
            acc[nj] = mfma16(ahi, bl, acc[nj]);
        }
    }
    const int rbase = m0 + ((lane >> 4) << 2);
    #pragma unroll
    for(int nj = 0; nj < 4; ++nj){
        const int n = n0 + nj*16 + nc;
        #pragma unroll
        for(int r = 0; r < 4; ++r) tmat[(size_t)(rbase + r)*H_ + n] = acc[nj][r];
    }
}

// ---------------- K4: scores[t,b,s] = tmat[t,b,:]·ctx[s,b,:]  (split-3) ------
__global__ __launch_bounds__(256) void k_scores(
    const float* __restrict__ tmat, const float* __restrict__ ctx,
    float* __restrict__ attn)
{
    const int b = blockIdx.y;
    const int lane = threadIdx.x & 63;
    const int wv = threadIdx.x >> 6;
    const int m0 = wv*16;             // T rows
    const int n0 = blockIdx.x*64;     // S cols
    const int kb = (lane >> 4) * 8;
    const int nc = lane & 15;
    const float* Ab = tmat + (size_t)b*H_;
    const float* Bb = ctx  + (size_t)b*H_;
    const int rowA = m0 + (lane & 15);
    f32x4 acc[4] = {zero4(), zero4(), zero4(), zero4()};
    for(int k0 = 0; k0 < H_; k0 += 32){
        short8 ahi, alo;
        load_cvt_frag(Ab + (size_t)rowA*(B_*H_) + k0 + kb, ahi, alo);
        #pragma unroll
        for(int nj = 0; nj < 4; ++nj){
            const int n = n0 + nj*16 + nc;
            short8 bhh, bll;
            load_cvt_frag(Bb + (size_t)n*(B_*H_) + k0 + kb, bhh, bll);
            acc[nj] = mfma16(ahi, bhh, acc[nj]);
            acc[nj] = mfma16(alo, bhh, acc[nj]);
            acc[nj] = mfma16(ahi, bll, acc[nj]);
        }
    }
    const int rbase = m0 + ((lane >> 4) << 2);
    #pragma unroll
    for(int nj = 0; nj < 4; ++nj){
        const int s = n0 + nj*16 + nc;
        #pragma unroll
        for(int r = 0; r < 4; ++r){
            const int t = rbase + r;
            attn[((size_t)t*B_ + b)*S_ + s] = acc[nj][r];
        }
    }
}

// ---------------- K5: row softmax over S, in-place on attn -------------------
__global__ __launch_bounds__(64) void k_softmax(float* __restrict__ attn){
    const int row = blockIdx.x;
    float* p = attn + (size_t)row*S_;
    const int lane = threadIdx.x;
    float v[8];
    float mx = -1e30f;
    #pragma unroll
    for(int i = 0; i < 8; ++i){ v[i] = p[lane + i*64]; mx = fmaxf(mx, v[i]); }
    #pragma unroll
    for(int o = 32; o; o >>= 1) mx = fmaxf(mx, __shfl_xor(mx, o));
    float sm = 0.f;
    #pragma unroll
    for(int i = 0; i < 8; ++i){ v[i] = expf(v[i] - mx); sm += v[i]; }
    #pragma unroll
    for(int o = 32; o; o >>= 1) sm += __shfl_xor(sm, o);
    const float inv = 1.f/sm;
    #pragma unroll
    for(int i = 0; i < 8; ++i) p[lane + i*64] = v[i]*inv;
}

// ---------------- K6: wc[t,b,h] = sum_s a[t,b,s]*ctx[s,b,h]  (plain bf16) ----
#define KP 40
__global__ __launch_bounds__(256) void k_wc(
    const float* __restrict__ attn, const float* __restrict__ ctx,
    float* __restrict__ wc)
{
    const int b = blockIdx.y;
    const int n0 = blockIdx.x*64;
    __shared__ alignas(16) short As[64*KP];
    __shared__ alignas(16) short Bs[64*KP];
    const int lane = threadIdx.x & 63;
    const int wv = threadIdx.x >> 6;
    const int m0 = wv*16;
    const int nc = lane & 15;
    const int kb = (lane >> 4) * 8;
    f32x4 acc[4] = {zero4(), zero4(), zero4(), zero4()};
    for(int k0 = 0; k0 < S_; k0 += 32){
        __syncthreads();
        #pragma unroll
        for(int p = 0; p < 2; ++p){
            int f4 = threadIdx.x + p*256;
            int row = f4 >> 3, kq = f4 & 7;
            const float* src = attn + ((size_t)row*B_ + b)*S_ + k0 + kq*4;
            f32x4 vv = *(const f32x4*)src;
            short4v s4;
            #pragma unroll
            for(int q = 0; q < 4; ++q) s4[q] = f2bf(vv[q]);
            *(short4v*)(As + row*KP + kq*4) = s4;
        }
        #pragma unroll
        for(int p = 0; p < 2; ++p){
            int f4 = threadIdx.x + p*256;
            int s = f4 >> 4, hq = f4 & 15;
            const float* src = ctx + ((size_t)(k0 + s)*B_ + b)*H_ + n0 + hq*4;
            f32x4 vv = *(const f32x4*)src;
            #pragma unroll
            for(int q = 0; q < 4; ++q) Bs[(hq*4 + q)*KP + s] = f2bf(vv[q]);
        }
        __syncthreads();
        const short8 af = *(const short8*)(As + (m0 + (lane & 15))*KP + kb);
        #pragma unroll
        for(int nj = 0; nj < 4; ++nj){
            const short8 bf = *(const short8*)(Bs + (nj*16 + nc)*KP + kb);
            acc[nj] = mfma16(af, bf, acc[nj]);
        }
    }
    const int rbase = m0 + ((lane >> 4) << 2);
    #pragma unroll
    for(int nj = 0; nj < 4; ++nj){
        const int h = n0 + nj*16 + nc;
        #pragma unroll
        for(int r = 0; r < 4; ++r){
            const int t = rbase + r;
            wc[((size_t)t*B_ + b)*H_ + h] = acc[nj][r];
        }
    }
}

// ---------------- K7: out = tanh(concat(wc,h) @ w_out^T) (plain bf16) --------
__global__ __launch_bounds__(256) void k_out(
    const float* __restrict__ wc,
    const short* __restrict__ h_hi,
    const short* __restrict__ wout_bf, float* __restrict__ outp)
{
    const int lane = threadIdx.x & 63;
    const int wv = threadIdx.x >> 6;
    const int m0 = blockIdx.x*64 + wv*16;
    const int n0 = blockIdx.y*64;
    const int rowA = m0 + (lane & 15);
    const int kb = (lane >> 4) * 8;
    const int nc = lane & 15;
    f32x4 acc[4] = {zero4(), zero4(), zero4(), zero4()};
    for(int kt = 0; kt < 32; ++kt){
        const int k0 = kt*32;
        short8 a;
        if (k0 < H_) a = load_cvt8(wc + (size_t)rowA*H_ + k0 + kb);
        else         a = *(const short8*)(h_hi + (size_t)(B_ + rowA)*H_ + (k0 - H_) + kb);
        #pragma unroll
        for(int nj = 0; nj < 4; ++nj){
            const int n = n0 + nj*16 + nc;
            const short8 bf = *(const short8*)(wout_bf + (size_t)n*(2*H_) + k0 + kb);
            acc[nj] = mfma16(a, bf, acc[nj]);
        }
    }
    const int rbase = m0 + ((lane >> 4) << 2);
    #pragma unroll
    for(int nj = 0; nj < 4; ++nj){
        const int n = n0 + nj*16 + nc;
        #pragma unroll
        for(int r = 0; r < 4; ++r) outp[(size_t)(rbase + r)*H_ + n] = tanhf(acc[nj][r]);
    }
}

// ---------------- K8: pgen at t = T-1 ----------------------------------------
__global__ __launch_bounds__(64) void k_pgen(
    const float* __restrict__ wc,
    const short* __restrict__ h_hi, const short* __restrict__ h_lo,
    const float* __restrict__ input, const float* __restrict__ w_pgen,
    const float* __restrict__ b_pgen, float* __restrict__ pg_out)
{
    const int b = blockIdx.x;
    const int lane = threadIdx.x;
    const float* wcb = wc    + ((size_t)(T_-1)*B_ + b)*H_;
    const size_t hbase = (size_t)(T_*B_ + b)*H_;   // slot T_, row b
    const float* xb  = input + ((size_t)(T_-1)*B_ + b)*E_;
    float s = 0.f;
    for(int k = lane; k < H_; k += 64) s += wcb[k]*w_pgen[k];
    for(int k = lane; k < H_; k += 64) s += (bf2f(h_hi[hbase+k]) + bf2f(h_lo[hbase+k]))*w_pgen[H_ + k];
    for(int k = lane; k < E_; k += 64) s += xb[k]*w_pgen[2*H_ + k];
    #pragma unroll
    for(int o = 32; o; o >>= 1) s += __shfl_xor(s, o);
    if(lane == 0) pg_out[b] = 1.f/(1.f + expf(-(s + b_pgen[0])));
}

extern "C" void kernel_launch(void* const* d_in, const int* in_sizes, int n_in,
                              void* d_out, int out_size, void* d_ws, size_t ws_size,
                              hipStream_t stream)
{
    const float* input  = (const float*)d_in[0];
    const float* hidden = (const float*)d_in[1];
    const float* ctx    = (const float*)d_in[2];
    const float* w_ih   = (const float*)d_in[3];
    const float* w_hh   = (const float*)d_in[4];
    const float* b_ih   = (const float*)d_in[5];
    const float* b_hh   = (const float*)d_in[6];
    const float* w_in   = (const float*)d_in[7];
    const float* w_out  = (const float*)d_in[8];
    const float* w_pgen = (const float*)d_in[9];
    const float* b_pgen = (const float*)d_in[10];

    float* outp = (float*)d_out;                       // (T,B,H)
    float* attn = outp + (size_t)T_*B_*H_;             // (T,B,S)
    float* pgo  = attn + (size_t)T_*B_*S_;             // (1,B,1)

    char* ws = (char*)d_ws;
    size_t off = 0;
    auto alloc = [&](size_t bytes) -> void* {
        void* p = ws + off; off += (bytes + 255) & ~(size_t)255; return p;
    };
    short* win_hi  = (short*)alloc((size_t)H_*H_*2);
    short* win_lo  = (short*)alloc((size_t)H_*H_*2);
    short* wout_bf = (short*)alloc((size_t)H_*2*H_*2);
    short* h_hi    = (short*)alloc((size_t)(T_+1)*B_*H_*2);   // 65 slots
    short* h_lo    = (short*)alloc((size_t)(T_+1)*B_*H_*2);
    short* x_hi    = (short*)alloc((size_t)T_*B_*E_*2);
    short* x_lo    = (short*)alloc((size_t)T_*B_*E_*2);
    unsigned* bar  = (unsigned*)alloc((size_t)T_*NG_*16*4);   // 64B-spaced counters
    float* tmat    = (float*)alloc((size_t)TB_*H_*4);         // 16.8 MB
    float* wcb     = tmat;   // alias: tmat dead after k_scores, wcb born at k_wc
    (void)ws_size; (void)in_sizes; (void)n_in; (void)out_size;
    // total ws ~44 MB (R3's proven-safe footprint was ~57 MB)

    k_prep<<<1024, 256, 0, stream>>>(w_in, w_out, hidden, input,
                                     win_hi, win_lo, wout_bf, h_hi, h_lo, x_hi, x_lo);

    hipMemsetAsync(bar, 0, (size_t)T_*NG_*16*4, stream);

    k_rec<<<NJ_*NG_, 192, 0, stream>>>(w_hh, w_ih, x_hi, x_lo,
                                       b_ih, b_hh, h_hi, h_lo, bar);

    k_tmat<<<dim3(128, 8), 256, 0, stream>>>(h_hi, h_lo, win_hi, win_lo, tmat);
    k_scores<<<dim3(8, 128), 256, 0, stream>>>(tmat, ctx, attn);
    k_softmax<<<8192, 64, 0, stream>>>(attn);
    k_wc<<<dim3(8, 128), 256, 0, stream>>>(attn, ctx, wcb);
    k_out<<<dim3(128, 8), 256, 0, stream>>>(wcb, h_hi, wout_bf, outp);
    k_pgen<<<128, 64, 0, stream>>>(wcb, h_hi, h_lo, input, w_pgen, b_pgen, pgo);
}